// Round 1
// baseline (285.042 us; speedup 1.0000x reference)
//
#include <hip/hip_runtime.h>

// MultiBoxLoss fused: SSD prior matching + smooth-L1 (positives) + focal loss (all).
// B=128 images, P=24564 priors, O=20 ground-truth boxes, 2 classes.
//
// Pipeline (all on `stream`):
//   init_ws      : zero packed-argmax array + accumulators
//   best_prior   : per (b,o) argmax_p IoU  -> packed (iou_bits<<32 | ~p), atomicMax
//   loss_kernel  : per (b,p) best-truth argmax over O (recomputed), fix-up vs
//                  best_prior, encode + smooth-L1 + focal, block-reduce, atomicAdd
//   finalize     : out[0]=loss_l/num_pos, out[1]=loss_c/num_pos

#define NB 128
#define NP 24564
#define NO 20

#define IPT1 12
#define NCH1 8            // ceil(24564 / (256*12))
#define IPT2 4
#define NCH2 24           // ceil(24564 / (256*4))

__global__ __launch_bounds__(256) void init_ws_kernel(unsigned long long* __restrict__ packed,
                                                      double* __restrict__ acc,
                                                      unsigned int* __restrict__ npos) {
    int i = blockIdx.x * 256 + threadIdx.x;
    if (i < NB * NO) packed[i] = 0ull;
    if (i == 0) { acc[0] = 0.0; acc[1] = 0.0; *npos = 0u; }
}

// Kernel 1: for each truth o of image b, argmax over priors p of IoU(truth, point_form(prior)).
// Key packs (iou_bits, ~p): atomicMax gives max IoU; ties -> smallest p (jnp.argmax first-occurrence).
__global__ __launch_bounds__(256) void best_prior_kernel(const float4* __restrict__ priors,
                                                         const float* __restrict__ bbox,
                                                         unsigned long long* __restrict__ packed) {
    const int b = blockIdx.x / NCH1;
    const int base = (blockIdx.x % NCH1) * (256 * IPT1);

    __shared__ float4 s_truth[NO];
    __shared__ float s_area[NO];
    if (threadIdx.x < NO) {
        const float* t = bbox + ((size_t)b * NO + threadIdx.x) * 5;
        float4 tb = make_float4(t[0], t[1], t[2], t[3]);
        s_truth[threadIdx.x] = tb;
        s_area[threadIdx.x] = (tb.z - tb.x) * (tb.w - tb.y);
    }
    __syncthreads();

    unsigned long long best[NO];
#pragma unroll
    for (int o = 0; o < NO; ++o) best[o] = 0ull;

    for (int k = 0; k < IPT1; ++k) {
        const int p = base + k * 256 + threadIdx.x;
        if (p < NP) {
            float4 pr = priors[p];  // center-form cx,cy,w,h
            float px0 = pr.x - pr.z * 0.5f, py0 = pr.y - pr.w * 0.5f;
            float px1 = pr.x + pr.z * 0.5f, py1 = pr.y + pr.w * 0.5f;
            float parea = (px1 - px0) * (py1 - py0);  // ref computes area from corners
            unsigned long long pkey = (unsigned long long)(0xFFFFFFFFu - (unsigned)p);
#pragma unroll
            for (int o = 0; o < NO; ++o) {
                float4 tb = s_truth[o];
                float lx = fmaxf(tb.x, px0), ly = fmaxf(tb.y, py0);
                float rx = fminf(tb.z, px1), ry = fminf(tb.w, py1);
                float w = fmaxf(rx - lx, 0.0f);
                float h = fmaxf(ry - ly, 0.0f);
                float inter = w * h;
                float iou = inter / (s_area[o] + parea - inter);  // denom > 0 always
                unsigned long long key =
                    ((unsigned long long)__float_as_uint(iou) << 32) | pkey;
                best[o] = (best[o] > key) ? best[o] : key;
            }
        }
    }

    // wave reduce (64 lanes) then one atomicMax per wave per truth
#pragma unroll
    for (int o = 0; o < NO; ++o) {
        unsigned long long v = best[o];
#pragma unroll
        for (int s = 32; s > 0; s >>= 1) {
            unsigned long long u = __shfl_xor(v, s, 64);
            v = (v > u) ? v : u;
        }
        if ((threadIdx.x & 63) == 0) atomicMax(&packed[b * NO + o], v);
    }
}

// Kernel 2: per prior: best truth (argmax over O, first-occurrence), fix-up with
// best_prior_idx (last-wins, matching scatter), conf/pos, encode + smooth-L1, focal.
__global__ __launch_bounds__(256) void loss_kernel(const float4* __restrict__ loc_data,
                                                   const float2* __restrict__ conf_data,
                                                   const float4* __restrict__ priors,
                                                   const float* __restrict__ bbox,
                                                   const unsigned long long* __restrict__ packed,
                                                   double* __restrict__ acc,
                                                   unsigned int* __restrict__ npos) {
    const int b = blockIdx.x / NCH2;
    const int base = (blockIdx.x % NCH2) * (256 * IPT2);

    __shared__ float4 s_truth[NO];
    __shared__ float s_area[NO];
    __shared__ int s_label[NO];
    __shared__ int s_bpi[NO];
    if (threadIdx.x < NO) {
        const float* t = bbox + ((size_t)b * NO + threadIdx.x) * 5;
        float4 tb = make_float4(t[0], t[1], t[2], t[3]);
        s_truth[threadIdx.x] = tb;
        s_area[threadIdx.x] = (tb.z - tb.x) * (tb.w - tb.y);
        s_label[threadIdx.x] = (int)t[4];
        unsigned long long v = packed[b * NO + threadIdx.x];
        s_bpi[threadIdx.x] = (int)(0xFFFFFFFFu - (unsigned)(v & 0xFFFFFFFFull));
    }
    __syncthreads();

    float lossl = 0.0f, lossc = 0.0f;
    int np = 0;

    for (int k = 0; k < IPT2; ++k) {
        const int p = base + k * 256 + threadIdx.x;
        if (p >= NP) continue;

        float4 pr = priors[p];
        float px0 = pr.x - pr.z * 0.5f, py0 = pr.y - pr.w * 0.5f;
        float px1 = pr.x + pr.z * 0.5f, py1 = pr.y + pr.w * 0.5f;
        float parea = (px1 - px0) * (py1 - py0);

        // argmax over truths, first occurrence (strict >, ascending o)
        float bestv = -1.0f;
        int bi = 0;
#pragma unroll
        for (int o = 0; o < NO; ++o) {
            float4 tb = s_truth[o];
            float lx = fmaxf(tb.x, px0), ly = fmaxf(tb.y, py0);
            float rx = fminf(tb.z, px1), ry = fminf(tb.w, py1);
            float w = fmaxf(rx - lx, 0.0f);
            float h = fmaxf(ry - ly, 0.0f);
            float inter = w * h;
            float iou = inter / (s_area[o] + parea - inter);
            if (iou > bestv) { bestv = iou; bi = o; }
        }
        // fix-up: each truth keeps its best prior (last-wins like XLA scatter)
#pragma unroll
        for (int o = 0; o < NO; ++o) {
            if (s_bpi[o] == p) { bestv = 2.0f; bi = o; }
        }

        bool thr = !(bestv < 0.5f);           // conf!=0 iff overlap >= THRESHOLD
        int conf = thr ? (s_label[bi] + 1) : 0;

        if (conf > 0) {
            np++;
            float4 m = s_truth[bi];           // matched GT, corner form
            float gx = ((m.x + m.z) * 0.5f - pr.x) / (0.1f * pr.z);
            float gy = ((m.y + m.w) * 0.5f - pr.y) / (0.1f * pr.w);
            float gw = logf((m.z - m.x) / pr.z) / 0.2f;
            float gh = logf((m.w - m.y) / pr.w) / 0.2f;
            float4 ld = loc_data[(size_t)b * NP + p];
            float d0 = ld.x - gx, d1 = ld.y - gy, d2 = ld.z - gw, d3 = ld.w - gh;
            float a0 = fabsf(d0), a1 = fabsf(d1), a2 = fabsf(d2), a3 = fabsf(d3);
            lossl += (a0 < 1.0f) ? 0.5f * d0 * d0 : a0 - 0.5f;
            lossl += (a1 < 1.0f) ? 0.5f * d1 * d1 : a1 - 0.5f;
            lossl += (a2 < 1.0f) ? 0.5f * d2 * d2 : a2 - 0.5f;
            lossl += (a3 < 1.0f) ? 0.5f * d3 * d3 : a3 - 0.5f;
        }

        // focal loss on every prior (pos_neg = conf_t > -1 is always true)
        float2 cd = conf_data[(size_t)b * NP + p];
        float mx = fmaxf(cd.x, cd.y);
        float e0 = expf(cd.x - mx), e1 = expf(cd.y - mx);
        float sum = e0 + e1;
        if (conf <= 1) {   // one_hot would be all-zero for conf >= 2
            float pc = ((conf == 0) ? e0 : e1) / sum;
            pc = fminf(fmaxf(pc, 1e-7f), 1.0f - 1e-7f);
            float om = 1.0f - pc;
            lossc += 0.25f * (-logf(pc)) * om * om;
        }
    }

    // block reduce: wave shfl, then LDS across 4 waves, then atomics
#pragma unroll
    for (int s = 32; s > 0; s >>= 1) {
        lossl += __shfl_xor(lossl, s, 64);
        lossc += __shfl_xor(lossc, s, 64);
        np    += __shfl_xor(np, s, 64);
    }
    __shared__ float s_ll[4], s_lc[4];
    __shared__ int s_np[4];
    int wid = threadIdx.x >> 6;
    if ((threadIdx.x & 63) == 0) { s_ll[wid] = lossl; s_lc[wid] = lossc; s_np[wid] = np; }
    __syncthreads();
    if (threadIdx.x == 0) {
        float tl = 0.0f, tc = 0.0f;
        int tn = 0;
        for (int w = 0; w < 4; ++w) { tl += s_ll[w]; tc += s_lc[w]; tn += s_np[w]; }
        atomicAdd(&acc[0], (double)tl);
        atomicAdd(&acc[1], (double)tc);
        atomicAdd(npos, (unsigned int)tn);
    }
}

__global__ __launch_bounds__(64) void finalize_kernel(const double* __restrict__ acc,
                                                      const unsigned int* __restrict__ npos,
                                                      float* __restrict__ out) {
    if (threadIdx.x == 0 && blockIdx.x == 0) {
        double np = (double)(*npos);
        if (np < 1.0) np = 1.0;
        out[0] = (float)(acc[0] / np);
        out[1] = (float)(acc[1] / np);
    }
}

extern "C" void kernel_launch(void* const* d_in, const int* in_sizes, int n_in,
                              void* d_out, int out_size, void* d_ws, size_t ws_size,
                              hipStream_t stream) {
    const float4* loc_data  = (const float4*)d_in[0];   // [B,P,4]
    const float2* conf_data = (const float2*)d_in[1];   // [B,P,2]
    const float4* priors    = (const float4*)d_in[2];   // [P,4]
    const float*  bbox      = (const float*)d_in[3];    // [B,O,5]
    float* out = (float*)d_out;

    unsigned long long* packed = (unsigned long long*)d_ws;                  // NB*NO u64
    double* acc = (double*)((char*)d_ws + (size_t)NB * NO * 8);              // 2 doubles
    unsigned int* npos = (unsigned int*)((char*)d_ws + (size_t)NB * NO * 8 + 16);

    init_ws_kernel<<<(NB * NO + 255) / 256, 256, 0, stream>>>(packed, acc, npos);
    best_prior_kernel<<<NB * NCH1, 256, 0, stream>>>(priors, bbox, packed);
    loss_kernel<<<NB * NCH2, 256, 0, stream>>>(loc_data, conf_data, priors, bbox,
                                               packed, acc, npos);
    finalize_kernel<<<1, 64, 0, stream>>>(acc, npos, out);
}